// Round 1
// baseline (138.518 us; speedup 1.0000x reference)
//
#include <hip/hip_runtime.h>
#include <math.h>

// PRNN J2 plane-strain elastoplasticity scan.
// B=16384, T=128, F=3, MATPTS=16 (P=262144), O=3.
// R11: max-parallelism layout — 1 material point per lane, 16 lanes/batch,
// 16 batches/block, grid=1024 (4 blocks/CU, 4 waves/SIMD; was 2). Counters
// showed VALUBusy 59% @ Occupancy 16% with HBM at 7.8%: latency-bound with
// grid-limited waves. Changes vs R10:
//  * unpacked scalar physics (1 pt/thread) -> 2x waves for latency hiding.
//  * trace-free-p identity: tr = wx0+wx1 (carry-FREE), c3 = tr/3 and the
//    deviatoric total-strain parts (wx-c3) hoist off the carry chain; the
//    chain loses the 3-FMA W1 multiply + tr path (~20-25 cyc/step).
//  * 16-lane DPP butterfly (adds row_mirror stage) for the Z reductions.
// Still: out(t) = M x(t) - 2MU Z(t); scaled yield Y; no LDS; broadcast
// float4 loads with distance-1 prefetch; predicated stores by lanes 0..2.

#define BLOCK 256
#define BPB 16              // batch elements per block (16 lanes each)
#define TSTEPS 128
#define ROWF (TSTEPS * 3)   // 384 floats per batch row

// schedulable fused-able DPP add stage: v += dpp_mov(v, ctrl), 0-fill
#define DPP_ADDST(v, ctrl)                                                   \
    v += __int_as_float(__builtin_amdgcn_update_dpp(                         \
        0, __float_as_int(v), (ctrl), 0xf, 0xf, true))
// 16-lane butterfly: quad_perm xor1 (0xB1), xor2 (0x4E),
// row_half_mirror (0x141), row_mirror (0x140)
#define RED16(v)                                                             \
    do { DPP_ADDST(v, 0xB1); DPP_ADDST(v, 0x4E);                             \
         DPP_ADDST(v, 0x141); DPP_ADDST(v, 0x140); } while (0)

// batched asm butterfly for the 12 in-loop partials
#define DPP_ST(r, ctrl) "v_add_f32_dpp %" #r ", %" #r ", %" #r " " ctrl \
                        " row_mask:0xf bank_mask:0xf\n\t"
#define DPP_STAGE(ctrl) \
    DPP_ST(0, ctrl) DPP_ST(1, ctrl) DPP_ST(2, ctrl)  DPP_ST(3, ctrl) \
    DPP_ST(4, ctrl) DPP_ST(5, ctrl) DPP_ST(6, ctrl)  DPP_ST(7, ctrl) \
    DPP_ST(8, ctrl) DPP_ST(9, ctrl) DPP_ST(10, ctrl) DPP_ST(11, ctrl)
#define DPP_BFLY12(a0,a1,a2,a3,a4,a5,a6,a7,a8,a9,a10,a11)                    \
  asm volatile(                                                              \
    "s_nop 1\n\t"                                                            \
    DPP_STAGE("quad_perm:[1,0,3,2]")                                         \
    DPP_STAGE("quad_perm:[2,3,0,1]")                                         \
    DPP_STAGE("row_half_mirror")                                             \
    DPP_STAGE("row_mirror")                                                  \
    : "+v"(a0), "+v"(a1), "+v"(a2), "+v"(a3), "+v"(a4), "+v"(a5),            \
      "+v"(a6), "+v"(a7), "+v"(a8), "+v"(a9), "+v"(a10), "+v"(a11))

__global__ __launch_bounds__(BLOCK, 4)
void prnn_j2_kernel(const float* __restrict__ x,
                    const float* __restrict__ W1,
                    const float* __restrict__ W2,
                    float* __restrict__ out)
{
    constexpr float MU    = (float)(3130.0 / (2.0 * (1.0 + 0.37)));
    constexpr float LAM   = (float)(3130.0 * 0.37 / ((1.0 + 0.37) * (1.0 - 2.0 * 0.37)));
    constexpr float SIG_Y = 64.8f;
    constexpr float H_ISO = 300.0f;
    const float TWO_MU  = 2.0f * MU;
    const float INV_DEN = 1.0f / (3.0f * MU + H_ISO);
    const float K3P     = (3.0f * MU) * INV_DEN;      // k = K3P * fY * rq
    const float HP      = H_ISO * INV_DEN;            // Y += HP * fY
    const float CSC     = 1.0f / (MU * 2.4494897427831781f);  // 1/(MU*sqrt6)
    const float Y0      = SIG_Y * CSC;

    const int tid = threadIdx.x;
    const int g   = tid >> 4;       // local batch 0..15
    const int l   = tid & 15;       // lane in 16-group = material point index
    const int gb  = blockIdx.x * BPB + g;   // global batch

    const float* xb = x + gb * ROWF;
    float* ob = out + gb * ROWF;

    // ---- per-point weights (1 point per lane) ----
    // w1 row 2 pre-halved (tensorial shear).
    float w1p[3][3], w2p[3][3];
    #pragma unroll
    for (int c = 0; c < 3; ++c)
        #pragma unroll
        for (int f = 0; f < 3; ++f) {
            float s = (c == 2) ? 0.5f : 1.0f;
            w1p[c][f] = s * W1[(3 * l + c) * 3 + f];
        }
    #pragma unroll
    for (int o = 0; o < 3; ++o)
        #pragma unroll
        for (int c = 0; c < 3; ++c) {
            float w = W2[o * 48 + 3 * l + c];
            w2p[o][c] = fmaxf(w, 0.0f) + log1pf(expf(-fabsf(w)));
        }

    // ---- constant elastic map M[o][f] = sum_p w2s_p . C . W1_p ----
    float Mrow[3];   // this lane's output-component row (l<3), else junk
    {
        float Ms[3][3];
        #pragma unroll
        for (int f = 0; f < 3; ++f) {
            float ax = (LAM + TWO_MU) * w1p[0][f] + LAM * w1p[1][f];
            float ay = LAM * w1p[0][f] + (LAM + TWO_MU) * w1p[1][f];
            float as = TWO_MU * w1p[2][f];
            #pragma unroll
            for (int o = 0; o < 3; ++o) {
                float ms = fmaf(w2p[o][0], ax,
                           fmaf(w2p[o][1], ay, w2p[o][2] * as));
                RED16(ms);              // sum over all 16 points
                Ms[o][f] = ms;
            }
        }
        #pragma unroll
        for (int f = 0; f < 3; ++f) {
            float v = (l == 0) ? Ms[0][f] : ((l == 1) ? Ms[1][f] : Ms[2][f]);
            Mrow[f] = v;
        }
    }

    float p0 = 0.f, p1 = 0.f, p2 = 0.f, p3 = 0.f;
    float Y  = Y0;
    float z0 = 0.f, z1 = 0.f, z2 = 0.f;

    const float4* xv = (const float4*)xb;   // group-uniform broadcast loads
    const bool wact = (l < 3);
    float* obl = ob + l;

// Carry chain: p0 -> exd -> u(tree,3) -> max -> rsq -> su -> fY -> k -> kdx -> p0.
// wx*, c3, (wx-c3) are pure functions of x (trace(p)==0 identically) and sit
// off the chain; szd = p2 + c3 joins with a single dependent op.
#define J2_PHYS(x0_, x1_, x2_, rr, mxv)                                      \
  {                                                                          \
    const float x0 = (x0_), x1 = (x1_), x2 = (x2_);                          \
    const float wx0 = fmaf(w1p[0][0], x0, fmaf(w1p[0][1], x1, w1p[0][2]*x2));\
    const float wx1 = fmaf(w1p[1][0], x0, fmaf(w1p[1][1], x1, w1p[1][2]*x2));\
    const float wxy = fmaf(w1p[2][0], x0, fmaf(w1p[2][1], x1, w1p[2][2]*x2));\
    const float c3  = (wx0 + wx1) * (1.0f / 3.0f);                           \
    const float ex0 = wx0 - c3;                                              \
    const float ey0 = wx1 - c3;                                              \
    const float exd = ex0 - p0;                                              \
    const float eyd = ey0 - p1;                                              \
    const float exy = wxy - p3;                                              \
    const float szd = p2 + c3;          /* = -ezd */                         \
    const float t2  = exy * exy;                                             \
    const float ua  = fmaf(eyd, eyd, exd * exd);                             \
    const float ub  = fmaf(t2, 2.0f, szd * szd);                             \
    float u = ua + ub;                                                       \
    u = fmaxf(u, 1e-30f);                                                    \
    const float rq = __builtin_amdgcn_rsqf(u);                               \
    const float su = u * rq;            /* sqrt(u) */                        \
    const float fY = fmaxf(su - Y, 0.0f);                                    \
    Y = fmaf(HP, fY, Y);                                                     \
    const float k = (K3P * fY) * rq;                                         \
    const float kdx  = k * exd;                                              \
    const float kdy  = k * eyd;                                              \
    const float kdxy = k * exy;                                              \
    p0 += kdx;                                                               \
    p1 += kdy;                                                               \
    p3 += kdxy;                                                              \
    p2 = fmaf(-k, szd, p2);                                                  \
    z0 = fmaf(w2p[0][0], kdx, fmaf(w2p[0][1], kdy, fmaf(w2p[0][2], kdxy, z0)));\
    z1 = fmaf(w2p[1][0], kdx, fmaf(w2p[1][1], kdy, fmaf(w2p[1][2], kdxy, z1)));\
    z2 = fmaf(w2p[2][0], kdx, fmaf(w2p[2][1], kdy, fmaf(w2p[2][2], kdxy, z2)));\
    (rr)[0] = z0;                                                            \
    (rr)[1] = z1;                                                            \
    (rr)[2] = z2;                                                            \
    (mxv) = fmaf(Mrow[0], x0, fmaf(Mrow[1], x1, Mrow[2] * x2));              \
  }

    float4 A0 = xv[0], A1 = xv[1], A2 = xv[2];

    for (int tb = 0; tb < TSTEPS / 4; ++tb) {
        // distance-1 prefetch; last iteration re-loads the same block (no OOB)
        const int nb = (tb < TSTEPS / 4 - 1) ? (3 * tb + 3) : (3 * tb);
        float4 An0 = xv[nb + 0];
        float4 An1 = xv[nb + 1];
        float4 An2 = xv[nb + 2];

        float r[12], mx[4];
        J2_PHYS(A0.x,  A0.y,  A0.z,  r + 0, mx[0]);
        J2_PHYS(A0.w,  A1.x,  A1.y,  r + 3, mx[1]);
        J2_PHYS(A1.z,  A1.w,  A2.x,  r + 6, mx[2]);
        J2_PHYS(A2.y,  A2.z,  A2.w,  r + 9, mx[3]);

        // sum the 12 cumulative-Z snapshots across the 16-lane group
        DPP_BFLY12(r[0], r[1], r[2], r[3], r[4], r[5],
                   r[6], r[7], r[8], r[9], r[10], r[11]);

        if (wact) {
            // lane l writes component l: out = M.x - 2MU * Z
            float zz0 = (l == 0) ? r[0] : ((l == 1) ? r[1]  : r[2]);
            float zz1 = (l == 0) ? r[3] : ((l == 1) ? r[4]  : r[5]);
            float zz2 = (l == 0) ? r[6] : ((l == 1) ? r[7]  : r[8]);
            float zz3 = (l == 0) ? r[9] : ((l == 1) ? r[10] : r[11]);
            obl[12 * tb + 0] = fmaf(-TWO_MU, zz0, mx[0]);
            obl[12 * tb + 3] = fmaf(-TWO_MU, zz1, mx[1]);
            obl[12 * tb + 6] = fmaf(-TWO_MU, zz2, mx[2]);
            obl[12 * tb + 9] = fmaf(-TWO_MU, zz3, mx[3]);
        }

        A0 = An0; A1 = An1; A2 = An2;
    }
#undef J2_PHYS
}

extern "C" void kernel_launch(void* const* d_in, const int* in_sizes, int n_in,
                              void* d_out, int out_size, void* d_ws, size_t ws_size,
                              hipStream_t stream) {
    const float* x  = (const float*)d_in[0];
    const float* W1 = (const float*)d_in[1];
    const float* W2 = (const float*)d_in[2];
    float* out = (float*)d_out;

    const int B = 16384;
    dim3 grid(B / BPB);   // 1024 blocks -> 4 blocks/CU, 4 waves/SIMD
    dim3 block(BLOCK);
    prnn_j2_kernel<<<grid, block, 0, stream>>>(x, W1, W2, out);
}

// Round 2
// 118.703 us; speedup vs baseline: 1.1669x; 1.1669x over previous
//
#include <hip/hip_runtime.h>
#include <math.h>

// PRNN J2 plane-strain elastoplasticity scan.
// B=16384, T=128, F=3, MATPTS=16 (P=262144), O=3.
// R12: R10 packed layout (2 points/thread in v2 -> v_pk_fma_f32, 8 lanes/batch,
// 32 batches/block, 2 waves/SIMD) + R11's carry-chain shortening.
// R11 post-mortem: scalarizing to 1pt/thread doubled waves (occ 16->27.5) but
// raised dynamic VALU cycles 1.65x (busy-units 35.7->59.1) -> net -36%. Packing
// is worth more than waves. The surviving R11 idea is the trace-free-p
// identity: trace(p)==0 identically, so tr = wx0+wx1 is carry-FREE; the W1
// 3-FMA chain, c3, and (wx-c3) hoist off the serial chain, which now opens
// with a single sub (exd = ex0 - p0). Chain/step ~72 -> ~52 cyc (-27%).
// Still: out(t) = M x(t) - 2MU Z(t); scaled yield Y; no LDS; broadcast
// float4 loads with distance-1 prefetch; predicated stores by lanes 0..2.

#define BLOCK 256
#define BPB 32              // batch elements per block (8 lanes each)
#define TSTEPS 128
#define ROWF (TSTEPS * 3)   // 384 floats per batch row

typedef float v2 __attribute__((ext_vector_type(2)));

static __device__ __forceinline__ v2 vfma(v2 a, v2 b, v2 c) {
    return __builtin_elementwise_fma(a, b, c);
}
static __device__ __forceinline__ v2 vmax(v2 a, v2 b) {
    return __builtin_elementwise_max(a, b);
}

// schedulable fused-able DPP add stage: v += dpp_mov(v, ctrl), 0-fill
#define DPP_ADDST(v, ctrl)                                                   \
    v += __int_as_float(__builtin_amdgcn_update_dpp(                         \
        0, __float_as_int(v), (ctrl), 0xf, 0xf, true))
// 8-lane butterfly: quad_perm xor1 (0xB1), xor2 (0x4E), row_half_mirror (0x141)
#define RED8(v)                                                              \
    do { DPP_ADDST(v, 0xB1); DPP_ADDST(v, 0x4E); DPP_ADDST(v, 0x141); } while (0)

// batched asm butterfly for the 12 in-loop partials (R7's best-measured form)
#define DPP_ST(r, ctrl) "v_add_f32_dpp %" #r ", %" #r ", %" #r " " ctrl \
                        " row_mask:0xf bank_mask:0xf\n\t"
#define DPP_STAGE(ctrl) \
    DPP_ST(0, ctrl) DPP_ST(1, ctrl) DPP_ST(2, ctrl)  DPP_ST(3, ctrl) \
    DPP_ST(4, ctrl) DPP_ST(5, ctrl) DPP_ST(6, ctrl)  DPP_ST(7, ctrl) \
    DPP_ST(8, ctrl) DPP_ST(9, ctrl) DPP_ST(10, ctrl) DPP_ST(11, ctrl)
#define DPP_BFLY12(a0,a1,a2,a3,a4,a5,a6,a7,a8,a9,a10,a11)                    \
  asm volatile(                                                              \
    "s_nop 1\n\t"                                                            \
    DPP_STAGE("quad_perm:[1,0,3,2]")                                         \
    DPP_STAGE("quad_perm:[2,3,0,1]")                                         \
    DPP_STAGE("row_half_mirror")                                             \
    : "+v"(a0), "+v"(a1), "+v"(a2), "+v"(a3), "+v"(a4), "+v"(a5),            \
      "+v"(a6), "+v"(a7), "+v"(a8), "+v"(a9), "+v"(a10), "+v"(a11))

__global__ __launch_bounds__(BLOCK, 2)
void prnn_j2_kernel(const float* __restrict__ x,
                    const float* __restrict__ W1,
                    const float* __restrict__ W2,
                    float* __restrict__ out)
{
    constexpr float MU    = (float)(3130.0 / (2.0 * (1.0 + 0.37)));
    constexpr float LAM   = (float)(3130.0 * 0.37 / ((1.0 + 0.37) * (1.0 - 2.0 * 0.37)));
    constexpr float SIG_Y = 64.8f;
    constexpr float H_ISO = 300.0f;
    const float TWO_MU  = 2.0f * MU;
    const float INV_DEN = 1.0f / (3.0f * MU + H_ISO);
    const float K3P     = (3.0f * MU) * INV_DEN;      // k = K3P * fY * rq_u
    const float HP      = H_ISO * INV_DEN;            // Y += HP * fY
    const float CSC     = 1.0f / (MU * 2.4494897427831781f);  // 1/(MU*sqrt6)
    const float Y0      = SIG_Y * CSC;

    const int tid = threadIdx.x;
    const int g   = tid >> 3;       // local batch 0..31
    const int l   = tid & 7;        // lane in 8-group; points (l, l+8)
    const int gb  = blockIdx.x * BPB + g;   // global batch

    const float* xb = x + gb * ROWF;
    float* ob = out + gb * ROWF;

    // ---- packed per-thread weights: .x = point l, .y = point l+8 ----
    // w1 row 2 pre-halved (tensorial shear).
    const int pa = l, pb = l + 8;
    v2 w1p[3][3], w2p[3][3];
    #pragma unroll
    for (int c = 0; c < 3; ++c)
        #pragma unroll
        for (int f = 0; f < 3; ++f) {
            float s = (c == 2) ? 0.5f : 1.0f;
            w1p[c][f].x = s * W1[(3 * pa + c) * 3 + f];
            w1p[c][f].y = s * W1[(3 * pb + c) * 3 + f];
        }
    #pragma unroll
    for (int o = 0; o < 3; ++o)
        #pragma unroll
        for (int c = 0; c < 3; ++c) {
            float wa = W2[o * 48 + 3 * pa + c];
            float wb = W2[o * 48 + 3 * pb + c];
            w2p[o][c].x = fmaxf(wa, 0.0f) + log1pf(expf(-fabsf(wa)));
            w2p[o][c].y = fmaxf(wb, 0.0f) + log1pf(expf(-fabsf(wb)));
        }

    // ---- constant elastic map M[o][f] = sum_p w2s_p . C . W1_p ----
    // (Ce)_xx row = (LAM+2MU) w1[0] + LAM w1[1];  yy analogous;
    // (Ce)_xy row = 2MU * w1p[2]  (w1p[2] already halved).
    float Mrow[3];   // this lane's output-component row (l<3), else junk
    {
        float Ms[3][3];
        #pragma unroll
        for (int f = 0; f < 3; ++f) {
            v2 ax = (LAM + TWO_MU) * w1p[0][f] + LAM * w1p[1][f];
            v2 ay = LAM * w1p[0][f] + (LAM + TWO_MU) * w1p[1][f];
            v2 as = TWO_MU * w1p[2][f];
            #pragma unroll
            for (int o = 0; o < 3; ++o) {
                v2 mp = vfma(w2p[o][0], ax, vfma(w2p[o][1], ay, w2p[o][2] * as));
                float ms = mp.x + mp.y;
                RED8(ms);               // sum over the 8 lanes (all 16 points)
                Ms[o][f] = ms;
            }
        }
        #pragma unroll
        for (int f = 0; f < 3; ++f) {
            float v = (l == 0) ? Ms[0][f] : ((l == 1) ? Ms[1][f] : Ms[2][f]);
            Mrow[f] = v;
        }
    }

    v2 p0 = {0.f,0.f}, p1 = {0.f,0.f}, p2 = {0.f,0.f}, p3 = {0.f,0.f};
    v2 Y  = {Y0, Y0};
    v2 z0 = {0.f,0.f}, z1 = {0.f,0.f}, z2 = {0.f,0.f};

    const float4* xv = (const float4*)xb;   // group-uniform broadcast loads
    const bool wact = (l < 3);
    float* obl = ob + l;

// Carry chain: p0 -> exd -> u(tree) -> max -> rsq -> su -> fY -> k -> kdx -> p0.
// wx*, c3, (wx-c3) are pure functions of x (trace(p)==0 identically) and sit
// off the chain; szd = p2 + c3 joins with a single dependent op.
#define J2_PHYS(x0_, x1_, x2_, rr, mxv)                                      \
  {                                                                          \
    const float x0s = (x0_), x1s = (x1_), x2s = (x2_);                       \
    const v2 x0 = {x0s, x0s}, x1 = {x1s, x1s}, x2 = {x2s, x2s};              \
    const v2 wx0 = vfma(w1p[0][0], x0, vfma(w1p[0][1], x1, w1p[0][2] * x2)); \
    const v2 wx1 = vfma(w1p[1][0], x0, vfma(w1p[1][1], x1, w1p[1][2] * x2)); \
    const v2 wxy = vfma(w1p[2][0], x0, vfma(w1p[2][1], x1, w1p[2][2] * x2)); \
    const v2 c3  = (wx0 + wx1) * (1.0f / 3.0f);                              \
    const v2 ex0 = wx0 - c3;                                                 \
    const v2 ey0 = wx1 - c3;                                                 \
    const v2 exd = ex0 - p0;                                                 \
    const v2 eyd = ey0 - p1;                                                 \
    const v2 exy = wxy - p3;                                                 \
    const v2 szd = p2 + c3;             /* = -ezd */                         \
    const v2 t2 = exy * exy;                                                 \
    const v2 ua = vfma(eyd, eyd, exd * exd);                                 \
    const v2 ub = vfma(t2, (v2){2.0f, 2.0f}, szd * szd);                     \
    v2 u = ua + ub;                                                          \
    u = vmax(u, (v2){1e-30f, 1e-30f});                                       \
    v2 rq;                                                                   \
    rq.x = __builtin_amdgcn_rsqf(u.x);                                       \
    rq.y = __builtin_amdgcn_rsqf(u.y);                                       \
    const v2 su = u * rq;               /* sqrt(u) */                        \
    const v2 fY = vmax(su - Y, (v2){0.0f, 0.0f});                            \
    Y = vfma((v2){HP, HP}, fY, Y);                                           \
    const v2 k = (K3P * fY) * rq;                                            \
    const v2 kdx = k * exd;                                                  \
    const v2 kdy = k * eyd;                                                  \
    const v2 kdxy = k * exy;                                                 \
    p0 += kdx;                                                               \
    p1 += kdy;                                                               \
    p3 += kdxy;                                                              \
    p2 = p2 - k * szd;                                                       \
    z0 = vfma(w2p[0][0], kdx, vfma(w2p[0][1], kdy, vfma(w2p[0][2], kdxy, z0)));\
    z1 = vfma(w2p[1][0], kdx, vfma(w2p[1][1], kdy, vfma(w2p[1][2], kdxy, z1)));\
    z2 = vfma(w2p[2][0], kdx, vfma(w2p[2][1], kdy, vfma(w2p[2][2], kdxy, z2)));\
    (rr)[0] = z0.x + z0.y;                                                   \
    (rr)[1] = z1.x + z1.y;                                                   \
    (rr)[2] = z2.x + z2.y;                                                   \
    (mxv) = fmaf(Mrow[0], x0s, fmaf(Mrow[1], x1s, Mrow[2] * x2s));           \
  }

    float4 A0 = xv[0], A1 = xv[1], A2 = xv[2];

    for (int tb = 0; tb < TSTEPS / 4; ++tb) {
        // distance-1 prefetch; last iteration re-loads the same block (no OOB)
        const int nb = (tb < TSTEPS / 4 - 1) ? (3 * tb + 3) : (3 * tb);
        float4 An0 = xv[nb + 0];
        float4 An1 = xv[nb + 1];
        float4 An2 = xv[nb + 2];

        float r[12], mx[4];
        J2_PHYS(A0.x,  A0.y,  A0.z,  r + 0, mx[0]);
        J2_PHYS(A0.w,  A1.x,  A1.y,  r + 3, mx[1]);
        J2_PHYS(A1.z,  A1.w,  A2.x,  r + 6, mx[2]);
        J2_PHYS(A2.y,  A2.z,  A2.w,  r + 9, mx[3]);

        // sum the 12 cumulative-Z snapshots across the 8-lane group
        DPP_BFLY12(r[0], r[1], r[2], r[3], r[4], r[5],
                   r[6], r[7], r[8], r[9], r[10], r[11]);

        if (wact) {
            // lane l writes component l: out = M.x - 2MU * Z
            float zz0 = (l == 0) ? r[0] : ((l == 1) ? r[1]  : r[2]);
            float zz1 = (l == 0) ? r[3] : ((l == 1) ? r[4]  : r[5]);
            float zz2 = (l == 0) ? r[6] : ((l == 1) ? r[7]  : r[8]);
            float zz3 = (l == 0) ? r[9] : ((l == 1) ? r[10] : r[11]);
            obl[12 * tb + 0] = fmaf(-TWO_MU, zz0, mx[0]);
            obl[12 * tb + 3] = fmaf(-TWO_MU, zz1, mx[1]);
            obl[12 * tb + 6] = fmaf(-TWO_MU, zz2, mx[2]);
            obl[12 * tb + 9] = fmaf(-TWO_MU, zz3, mx[3]);
        }

        A0 = An0; A1 = An1; A2 = An2;
    }
#undef J2_PHYS
}

extern "C" void kernel_launch(void* const* d_in, const int* in_sizes, int n_in,
                              void* d_out, int out_size, void* d_ws, size_t ws_size,
                              hipStream_t stream) {
    const float* x  = (const float*)d_in[0];
    const float* W1 = (const float*)d_in[1];
    const float* W2 = (const float*)d_in[2];
    float* out = (float*)d_out;

    const int B = 16384;
    dim3 grid(B / BPB);   // 512 blocks, 2 waves/SIMD
    dim3 block(BLOCK);
    prnn_j2_kernel<<<grid, block, 0, stream>>>(x, W1, W2, out);
}

// Round 3
// 116.468 us; speedup vs baseline: 1.1893x; 1.0192x over previous
//
#include <hip/hip_runtime.h>
#include <math.h>

// PRNN J2 plane-strain elastoplasticity scan.
// B=16384, T=128, F=3, MATPTS=16 (P=262144), O=3.
// R13: packed layout (2 pts/thread v2, 8 lanes/batch, 32 batches/block,
// 2 waves/SIMD) + op DELETION + unroll-8.
// R12 post-mortem: chain-shortening alone was NEUTRAL (60.0 vs 60.5 us) ->
// not purely chain-latency-bound; compiler already fills stalls within the
// 4-step window. R13 removes instructions outright and widens the window:
//  * deviatoric W1 rows precomputed (ex0 = w1dx.x directly): c3/ex0/ey0
//    subs gone; szd = exd + eyd (exact, trace(p)==0) -> p2 state deleted.
//  * sqrt2-folded shear: ps = sqrt2*p3, exy2 = wsh.x - ps, u uses exy2^2
//    directly (t2 mul deleted); w2 shear col pre-scaled by 1/sqrt2.
//  * yield: g = fma(-Y,rq,1) = (su-Y)*rq -> k = K3P*max(g,0) needs no su;
//    fY = gm*su only feeds the Y side-chain. Chain-to-kd 6 -> 4 deep.
//  * unroll 8 steps/iter: the volatile-asm butterfly is a scheduling
//    barrier, so window doubles; one 24-value butterfly per 8 steps.
// Still: out(t) = M x(t) - 2MU Z(t); no LDS; broadcast float4 loads with
// distance-1 prefetch; predicated stores by lanes 0..2.

#define BLOCK 256
#define BPB 32              // batch elements per block (8 lanes each)
#define TSTEPS 128
#define ROWF (TSTEPS * 3)   // 384 floats per batch row

typedef float v2 __attribute__((ext_vector_type(2)));

static __device__ __forceinline__ v2 vfma(v2 a, v2 b, v2 c) {
    return __builtin_elementwise_fma(a, b, c);
}
static __device__ __forceinline__ v2 vmax(v2 a, v2 b) {
    return __builtin_elementwise_max(a, b);
}

// schedulable DPP add stage: v += dpp_mov(v, ctrl), 0-fill (init-only use)
#define DPP_ADDST(v, ctrl)                                                   \
    v += __int_as_float(__builtin_amdgcn_update_dpp(                         \
        0, __float_as_int(v), (ctrl), 0xf, 0xf, true))
// 8-lane butterfly: quad_perm xor1 (0xB1), xor2 (0x4E), row_half_mirror (0x141)
#define RED8(v)                                                              \
    do { DPP_ADDST(v, 0xB1); DPP_ADDST(v, 0x4E); DPP_ADDST(v, 0x141); } while (0)

// batched asm butterfly for the 24 in-loop partials
#define DPP_ST(r, ctrl) "v_add_f32_dpp %" #r ", %" #r ", %" #r " " ctrl \
                        " row_mask:0xf bank_mask:0xf\n\t"
#define DPP_STAGE24(ctrl) \
    DPP_ST(0, ctrl)  DPP_ST(1, ctrl)  DPP_ST(2, ctrl)  DPP_ST(3, ctrl)  \
    DPP_ST(4, ctrl)  DPP_ST(5, ctrl)  DPP_ST(6, ctrl)  DPP_ST(7, ctrl)  \
    DPP_ST(8, ctrl)  DPP_ST(9, ctrl)  DPP_ST(10, ctrl) DPP_ST(11, ctrl) \
    DPP_ST(12, ctrl) DPP_ST(13, ctrl) DPP_ST(14, ctrl) DPP_ST(15, ctrl) \
    DPP_ST(16, ctrl) DPP_ST(17, ctrl) DPP_ST(18, ctrl) DPP_ST(19, ctrl) \
    DPP_ST(20, ctrl) DPP_ST(21, ctrl) DPP_ST(22, ctrl) DPP_ST(23, ctrl)
#define DPP_BFLY24(a0,a1,a2,a3,a4,a5,a6,a7,a8,a9,a10,a11,                    \
                   a12,a13,a14,a15,a16,a17,a18,a19,a20,a21,a22,a23)          \
  asm volatile(                                                              \
    "s_nop 1\n\t"                                                            \
    DPP_STAGE24("quad_perm:[1,0,3,2]")                                       \
    DPP_STAGE24("quad_perm:[2,3,0,1]")                                       \
    DPP_STAGE24("row_half_mirror")                                           \
    : "+v"(a0), "+v"(a1), "+v"(a2), "+v"(a3), "+v"(a4), "+v"(a5),            \
      "+v"(a6), "+v"(a7), "+v"(a8), "+v"(a9), "+v"(a10), "+v"(a11),          \
      "+v"(a12), "+v"(a13), "+v"(a14), "+v"(a15), "+v"(a16), "+v"(a17),      \
      "+v"(a18), "+v"(a19), "+v"(a20), "+v"(a21), "+v"(a22), "+v"(a23))

__global__ __launch_bounds__(BLOCK, 2)
void prnn_j2_kernel(const float* __restrict__ x,
                    const float* __restrict__ W1,
                    const float* __restrict__ W2,
                    float* __restrict__ out)
{
    constexpr float MU    = (float)(3130.0 / (2.0 * (1.0 + 0.37)));
    constexpr float LAM   = (float)(3130.0 * 0.37 / ((1.0 + 0.37) * (1.0 - 2.0 * 0.37)));
    constexpr float SIG_Y = 64.8f;
    constexpr float H_ISO = 300.0f;
    const float TWO_MU  = 2.0f * MU;
    const float INV_DEN = 1.0f / (3.0f * MU + H_ISO);
    const float K3P     = (3.0f * MU) * INV_DEN;      // k = K3P * gm
    const float HP      = H_ISO * INV_DEN;            // Y += HP * fY
    const float CSC     = 1.0f / (MU * 2.4494897427831781f);  // 1/(MU*sqrt6)
    const float Y0      = SIG_Y * CSC;
    const float SQRT2   = 1.41421356237309515f;
    const float RSQRT2  = 0.70710678118654752f;

    const int tid = threadIdx.x;
    const int g   = tid >> 3;       // local batch 0..31
    const int l   = tid & 7;        // lane in 8-group; points (l, l+8)
    const int gb  = blockIdx.x * BPB + g;   // global batch

    const float* xb = x + gb * ROWF;
    float* ob = out + gb * ROWF;

    // ---- packed per-thread weights: .x = point l, .y = point l+8 ----
    const int pa = l, pb = l + 8;
    v2 w1r0[3], w1r1[3], w1h2[3];      // raw row0, row1, half row2
    #pragma unroll
    for (int f = 0; f < 3; ++f) {
        w1r0[f].x = W1[(3 * pa + 0) * 3 + f];
        w1r0[f].y = W1[(3 * pb + 0) * 3 + f];
        w1r1[f].x = W1[(3 * pa + 1) * 3 + f];
        w1r1[f].y = W1[(3 * pb + 1) * 3 + f];
        w1h2[f].x = 0.5f * W1[(3 * pa + 2) * 3 + f];
        w1h2[f].y = 0.5f * W1[(3 * pb + 2) * 3 + f];
    }
    v2 w2p[3][3];
    #pragma unroll
    for (int o = 0; o < 3; ++o)
        #pragma unroll
        for (int c = 0; c < 3; ++c) {
            float wa = W2[o * 48 + 3 * pa + c];
            float wb = W2[o * 48 + 3 * pb + c];
            w2p[o][c].x = fmaxf(wa, 0.0f) + log1pf(expf(-fabsf(wa)));
            w2p[o][c].y = fmaxf(wb, 0.0f) + log1pf(expf(-fabsf(wb)));
        }

    // ---- constant elastic map M[o][f] = sum_p w2s_p . C . W1_p ----
    float Mrow[3];   // this lane's output-component row (l<3), else junk
    {
        float Ms[3][3];
        #pragma unroll
        for (int f = 0; f < 3; ++f) {
            v2 ax = (LAM + TWO_MU) * w1r0[f] + LAM * w1r1[f];
            v2 ay = LAM * w1r0[f] + (LAM + TWO_MU) * w1r1[f];
            v2 as = TWO_MU * w1h2[f];
            #pragma unroll
            for (int o = 0; o < 3; ++o) {
                v2 mp = vfma(w2p[o][0], ax, vfma(w2p[o][1], ay, w2p[o][2] * as));
                float ms = mp.x + mp.y;
                RED8(ms);               // sum over the 8 lanes (all 16 points)
                Ms[o][f] = ms;
            }
        }
        #pragma unroll
        for (int f = 0; f < 3; ++f) {
            float v = (l == 0) ? Ms[0][f] : ((l == 1) ? Ms[1][f] : Ms[2][f]);
            Mrow[f] = v;
        }
    }

    // ---- loop-form weights: deviatoric rows + sqrt2-folded shear ----
    v2 wdx[3], wdy[3], wsh[3];
    #pragma unroll
    for (int f = 0; f < 3; ++f) {
        wdx[f] = (2.0f * w1r0[f] - w1r1[f]) * (1.0f / 3.0f);  // ex0 = wdx.x
        wdy[f] = (2.0f * w1r1[f] - w1r0[f]) * (1.0f / 3.0f);  // ey0 = wdy.x
        wsh[f] = SQRT2 * w1h2[f];                              // exy2-elastic
    }
    #pragma unroll
    for (int o = 0; o < 3; ++o) w2p[o][2] *= RSQRT2;  // dps = sqrt2*dp3

    v2 p0 = {0.f,0.f}, p1 = {0.f,0.f}, ps = {0.f,0.f};
    v2 Y  = {Y0, Y0};
    v2 z0 = {0.f,0.f}, z1 = {0.f,0.f}, z2 = {0.f,0.f};

    const float4* xv = (const float4*)xb;   // group-uniform broadcast loads
    const bool wact = (l < 3);
    float* obl = ob + l;

// Carry chain: p0 -> exd -> ua -> u -> max -> rq -> g -> gm -> k -> kdx -> p0.
// ex0/ey0/wsy are pure functions of x (off-chain); szd = exd + eyd is exact
// (trace(p)==0); fY = gm*su only feeds the Y side-chain.
#define J2_PHYS(x0_, x1_, x2_, rr, mxv)                                      \
  {                                                                          \
    const float x0s = (x0_), x1s = (x1_), x2s = (x2_);                       \
    const v2 x0 = {x0s, x0s}, x1 = {x1s, x1s}, x2 = {x2s, x2s};              \
    const v2 ex0 = vfma(wdx[0], x0, vfma(wdx[1], x1, wdx[2] * x2));          \
    const v2 ey0 = vfma(wdy[0], x0, vfma(wdy[1], x1, wdy[2] * x2));          \
    const v2 wsy = vfma(wsh[0], x0, vfma(wsh[1], x1, wsh[2] * x2));          \
    const v2 exd = ex0 - p0;                                                 \
    const v2 eyd = ey0 - p1;                                                 \
    const v2 exy = wsy - ps;                                                 \
    const v2 szd = exd + eyd;           /* = -ezd, exact */                  \
    const v2 ua = vfma(eyd, eyd, exd * exd);                                 \
    const v2 ub = vfma(exy, exy, szd * szd);                                 \
    v2 u = ua + ub;                                                          \
    u = vmax(u, (v2){1e-30f, 1e-30f});                                       \
    v2 rq;                                                                   \
    rq.x = __builtin_amdgcn_rsqf(u.x);                                       \
    rq.y = __builtin_amdgcn_rsqf(u.y);                                       \
    const v2 gm = vmax(vfma(-Y, rq, (v2){1.0f, 1.0f}), (v2){0.0f, 0.0f});    \
    const v2 su = u * rq;               /* sqrt(u), Y side-chain only */     \
    const v2 k  = K3P * gm;                                                  \
    Y = vfma((v2){HP, HP}, gm * su, Y); /* fY = gm*su = max(su-Y,0) */       \
    const v2 kdx = k * exd;                                                  \
    const v2 kdy = k * eyd;                                                  \
    const v2 kdp = k * exy;                                                  \
    p0 += kdx;                                                               \
    p1 += kdy;                                                               \
    ps += kdp;                                                               \
    z0 = vfma(w2p[0][0], kdx, vfma(w2p[0][1], kdy, vfma(w2p[0][2], kdp, z0)));\
    z1 = vfma(w2p[1][0], kdx, vfma(w2p[1][1], kdy, vfma(w2p[1][2], kdp, z1)));\
    z2 = vfma(w2p[2][0], kdx, vfma(w2p[2][1], kdy, vfma(w2p[2][2], kdp, z2)));\
    (rr)[0] = z0.x + z0.y;                                                   \
    (rr)[1] = z1.x + z1.y;                                                   \
    (rr)[2] = z2.x + z2.y;                                                   \
    (mxv) = fmaf(Mrow[0], x0s, fmaf(Mrow[1], x1s, Mrow[2] * x2s));           \
  }

    float4 A0 = xv[0], A1 = xv[1], A2 = xv[2];
    float4 A3 = xv[3], A4 = xv[4], A5 = xv[5];

    for (int tb = 0; tb < TSTEPS / 8; ++tb) {
        // distance-1 prefetch; last iteration re-loads the same block (no OOB)
        const int nb = (tb < TSTEPS / 8 - 1) ? (6 * tb + 6) : (6 * tb);
        float4 An0 = xv[nb + 0];
        float4 An1 = xv[nb + 1];
        float4 An2 = xv[nb + 2];
        float4 An3 = xv[nb + 3];
        float4 An4 = xv[nb + 4];
        float4 An5 = xv[nb + 5];

        float r[24], mx[8];
        J2_PHYS(A0.x, A0.y, A0.z, r + 0,  mx[0]);
        J2_PHYS(A0.w, A1.x, A1.y, r + 3,  mx[1]);
        J2_PHYS(A1.z, A1.w, A2.x, r + 6,  mx[2]);
        J2_PHYS(A2.y, A2.z, A2.w, r + 9,  mx[3]);
        J2_PHYS(A3.x, A3.y, A3.z, r + 12, mx[4]);
        J2_PHYS(A3.w, A4.x, A4.y, r + 15, mx[5]);
        J2_PHYS(A4.z, A4.w, A5.x, r + 18, mx[6]);
        J2_PHYS(A5.y, A5.z, A5.w, r + 21, mx[7]);

        // sum the 24 cumulative-Z snapshots across the 8-lane group
        DPP_BFLY24(r[0],  r[1],  r[2],  r[3],  r[4],  r[5],
                   r[6],  r[7],  r[8],  r[9],  r[10], r[11],
                   r[12], r[13], r[14], r[15], r[16], r[17],
                   r[18], r[19], r[20], r[21], r[22], r[23]);

        if (wact) {
            // lane l writes component l: out = M.x - 2MU * Z
            #pragma unroll
            for (int s = 0; s < 8; ++s) {
                float zz = (l == 0) ? r[3*s] : ((l == 1) ? r[3*s+1] : r[3*s+2]);
                obl[24 * tb + 3 * s] = fmaf(-TWO_MU, zz, mx[s]);
            }
        }

        A0 = An0; A1 = An1; A2 = An2;
        A3 = An3; A4 = An4; A5 = An5;
    }
#undef J2_PHYS
}

extern "C" void kernel_launch(void* const* d_in, const int* in_sizes, int n_in,
                              void* d_out, int out_size, void* d_ws, size_t ws_size,
                              hipStream_t stream) {
    const float* x  = (const float*)d_in[0];
    const float* W1 = (const float*)d_in[1];
    const float* W2 = (const float*)d_in[2];
    float* out = (float*)d_out;

    const int B = 16384;
    dim3 grid(B / BPB);   // 512 blocks, 2 waves/SIMD
    dim3 block(BLOCK);
    prnn_j2_kernel<<<grid, block, 0, stream>>>(x, W1, W2, out);
}

// Round 4
// 115.032 us; speedup vs baseline: 1.2042x; 1.0125x over previous
//
#include <hip/hip_runtime.h>
#include <math.h>

// PRNN J2 plane-strain elastoplasticity scan.
// B=16384, T=128, F=3, MATPTS=16 (P=262144), O=3.
// R14: 2-BATCH-PER-THREAD ILP experiment at constant total issue.
// Evidence: R12 (chain shortening) null, R13 (15% op deletion) gave only 8%
// -> large stall component that op count can't reach. v2 packing confirmed
// real (R11 busy-ratio 1.65x matches packed->scalar arithmetic). Weights are
// batch-invariant, so a thread can run TWO batches' independent chains with
// zero extra weight regs and zero extra instructions per chain: threads
// halve (grid 256, 1 block/CU, 1 wave/SIMD), per-SIMD VALU work unchanged,
// but each chain stall is filled by the sibling batch's stream in-window
// (instead of a co-wave that stalls in phase).
//  * layout: 8 lanes/batch, 2 pts/lane (v2), batches (gbA, gbA+32)/thread.
//  * physics unchanged from R13 (deviatoric W1 rows, sqrt2-folded shear,
//    g = fma(-Y,rq,1) yield form, trace-free-p identity).
//  * unroll 8; two DPP_BFLY24 per body (one per batch).
// Still: out(t) = M x(t) - 2MU Z(t); no LDS; broadcast float4 loads with
// distance-1 prefetch; predicated stores by lanes 0..2.

#define BLOCK 256
#define BPB 64              // batch elements per block (8 lanes, 2 per thread)
#define TSTEPS 128
#define ROWF (TSTEPS * 3)   // 384 floats per batch row

typedef float v2 __attribute__((ext_vector_type(2)));

static __device__ __forceinline__ v2 vfma(v2 a, v2 b, v2 c) {
    return __builtin_elementwise_fma(a, b, c);
}
static __device__ __forceinline__ v2 vmax(v2 a, v2 b) {
    return __builtin_elementwise_max(a, b);
}

// schedulable DPP add stage: v += dpp_mov(v, ctrl), 0-fill (init-only use)
#define DPP_ADDST(v, ctrl)                                                   \
    v += __int_as_float(__builtin_amdgcn_update_dpp(                         \
        0, __float_as_int(v), (ctrl), 0xf, 0xf, true))
// 8-lane butterfly: quad_perm xor1 (0xB1), xor2 (0x4E), row_half_mirror (0x141)
#define RED8(v)                                                              \
    do { DPP_ADDST(v, 0xB1); DPP_ADDST(v, 0x4E); DPP_ADDST(v, 0x141); } while (0)

// batched asm butterfly for 24 in-loop partials
#define DPP_ST(r, ctrl) "v_add_f32_dpp %" #r ", %" #r ", %" #r " " ctrl \
                        " row_mask:0xf bank_mask:0xf\n\t"
#define DPP_STAGE24(ctrl) \
    DPP_ST(0, ctrl)  DPP_ST(1, ctrl)  DPP_ST(2, ctrl)  DPP_ST(3, ctrl)  \
    DPP_ST(4, ctrl)  DPP_ST(5, ctrl)  DPP_ST(6, ctrl)  DPP_ST(7, ctrl)  \
    DPP_ST(8, ctrl)  DPP_ST(9, ctrl)  DPP_ST(10, ctrl) DPP_ST(11, ctrl) \
    DPP_ST(12, ctrl) DPP_ST(13, ctrl) DPP_ST(14, ctrl) DPP_ST(15, ctrl) \
    DPP_ST(16, ctrl) DPP_ST(17, ctrl) DPP_ST(18, ctrl) DPP_ST(19, ctrl) \
    DPP_ST(20, ctrl) DPP_ST(21, ctrl) DPP_ST(22, ctrl) DPP_ST(23, ctrl)
#define DPP_BFLY24(a0,a1,a2,a3,a4,a5,a6,a7,a8,a9,a10,a11,                    \
                   a12,a13,a14,a15,a16,a17,a18,a19,a20,a21,a22,a23)          \
  asm volatile(                                                              \
    "s_nop 1\n\t"                                                            \
    DPP_STAGE24("quad_perm:[1,0,3,2]")                                       \
    DPP_STAGE24("quad_perm:[2,3,0,1]")                                       \
    DPP_STAGE24("row_half_mirror")                                           \
    : "+v"(a0), "+v"(a1), "+v"(a2), "+v"(a3), "+v"(a4), "+v"(a5),            \
      "+v"(a6), "+v"(a7), "+v"(a8), "+v"(a9), "+v"(a10), "+v"(a11),          \
      "+v"(a12), "+v"(a13), "+v"(a14), "+v"(a15), "+v"(a16), "+v"(a17),      \
      "+v"(a18), "+v"(a19), "+v"(a20), "+v"(a21), "+v"(a22), "+v"(a23))

__global__ __launch_bounds__(BLOCK, 1)
void prnn_j2_kernel(const float* __restrict__ x,
                    const float* __restrict__ W1,
                    const float* __restrict__ W2,
                    float* __restrict__ out)
{
    constexpr float MU    = (float)(3130.0 / (2.0 * (1.0 + 0.37)));
    constexpr float LAM   = (float)(3130.0 * 0.37 / ((1.0 + 0.37) * (1.0 - 2.0 * 0.37)));
    constexpr float SIG_Y = 64.8f;
    constexpr float H_ISO = 300.0f;
    const float TWO_MU  = 2.0f * MU;
    const float INV_DEN = 1.0f / (3.0f * MU + H_ISO);
    const float K3P     = (3.0f * MU) * INV_DEN;      // k = K3P * gm
    const float HP      = H_ISO * INV_DEN;            // Y += HP * fY
    const float CSC     = 1.0f / (MU * 2.4494897427831781f);  // 1/(MU*sqrt6)
    const float Y0      = SIG_Y * CSC;
    const float SQRT2   = 1.41421356237309515f;
    const float RSQRT2  = 0.70710678118654752f;

    const int tid = threadIdx.x;
    const int g   = tid >> 3;       // local batch 0..31
    const int l   = tid & 7;        // lane in 8-group; points (l, l+8)
    const int gbA = blockIdx.x * BPB + g;        // batch A
    const int gbB = gbA + 32;                    // batch B

    const float* xbA = x + gbA * ROWF;
    const float* xbB = x + gbB * ROWF;
    float* obA = out + gbA * ROWF;
    float* obB = out + gbB * ROWF;

    // ---- packed per-point weights (shared by both batches) ----
    const int pa = l, pb = l + 8;
    v2 w1r0[3], w1r1[3], w1h2[3];      // raw row0, row1, half row2
    #pragma unroll
    for (int f = 0; f < 3; ++f) {
        w1r0[f].x = W1[(3 * pa + 0) * 3 + f];
        w1r0[f].y = W1[(3 * pb + 0) * 3 + f];
        w1r1[f].x = W1[(3 * pa + 1) * 3 + f];
        w1r1[f].y = W1[(3 * pb + 1) * 3 + f];
        w1h2[f].x = 0.5f * W1[(3 * pa + 2) * 3 + f];
        w1h2[f].y = 0.5f * W1[(3 * pb + 2) * 3 + f];
    }
    v2 w2p[3][3];
    #pragma unroll
    for (int o = 0; o < 3; ++o)
        #pragma unroll
        for (int c = 0; c < 3; ++c) {
            float wa = W2[o * 48 + 3 * pa + c];
            float wb = W2[o * 48 + 3 * pb + c];
            w2p[o][c].x = fmaxf(wa, 0.0f) + log1pf(expf(-fabsf(wa)));
            w2p[o][c].y = fmaxf(wb, 0.0f) + log1pf(expf(-fabsf(wb)));
        }

    // ---- constant elastic map M[o][f] = sum_p w2s_p . C . W1_p ----
    float Mrow[3];   // this lane's output-component row (l<3), else junk
    {
        float Ms[3][3];
        #pragma unroll
        for (int f = 0; f < 3; ++f) {
            v2 ax = (LAM + TWO_MU) * w1r0[f] + LAM * w1r1[f];
            v2 ay = LAM * w1r0[f] + (LAM + TWO_MU) * w1r1[f];
            v2 as = TWO_MU * w1h2[f];
            #pragma unroll
            for (int o = 0; o < 3; ++o) {
                v2 mp = vfma(w2p[o][0], ax, vfma(w2p[o][1], ay, w2p[o][2] * as));
                float ms = mp.x + mp.y;
                RED8(ms);               // sum over the 8 lanes (all 16 points)
                Ms[o][f] = ms;
            }
        }
        #pragma unroll
        for (int f = 0; f < 3; ++f) {
            float v = (l == 0) ? Ms[0][f] : ((l == 1) ? Ms[1][f] : Ms[2][f]);
            Mrow[f] = v;
        }
    }

    // ---- loop-form weights: deviatoric rows + sqrt2-folded shear ----
    v2 wdx[3], wdy[3], wsh[3];
    #pragma unroll
    for (int f = 0; f < 3; ++f) {
        wdx[f] = (2.0f * w1r0[f] - w1r1[f]) * (1.0f / 3.0f);  // ex0 = wdx.x
        wdy[f] = (2.0f * w1r1[f] - w1r0[f]) * (1.0f / 3.0f);  // ey0 = wdy.x
        wsh[f] = SQRT2 * w1h2[f];                              // exy2-elastic
    }
    #pragma unroll
    for (int o = 0; o < 3; ++o) w2p[o][2] *= RSQRT2;  // dps = sqrt2*dp3

    // ---- per-batch state ----
    v2 pA0 = {0.f,0.f}, pA1 = {0.f,0.f}, pAs = {0.f,0.f};
    v2 YA  = {Y0, Y0};
    v2 zA0 = {0.f,0.f}, zA1 = {0.f,0.f}, zA2 = {0.f,0.f};
    v2 pB0 = {0.f,0.f}, pB1 = {0.f,0.f}, pBs = {0.f,0.f};
    v2 YB  = {Y0, Y0};
    v2 zB0 = {0.f,0.f}, zB1 = {0.f,0.f}, zB2 = {0.f,0.f};

    const float4* xvA = (const float4*)xbA;  // group-uniform broadcast loads
    const float4* xvB = (const float4*)xbB;
    const bool wact = (l < 3);
    float* oblA = obA + l;
    float* oblB = obB + l;

// Carry chain: P0 -> exd -> ua -> u -> max -> rq -> g -> gm -> k -> kdx -> P0.
#define J2_PHYS(P0, P1, PS, YY, Z0, Z1, Z2, x0_, x1_, x2_, rr, mxv)          \
  {                                                                          \
    const float x0s = (x0_), x1s = (x1_), x2s = (x2_);                       \
    const v2 x0 = {x0s, x0s}, x1 = {x1s, x1s}, x2 = {x2s, x2s};              \
    const v2 ex0 = vfma(wdx[0], x0, vfma(wdx[1], x1, wdx[2] * x2));          \
    const v2 ey0 = vfma(wdy[0], x0, vfma(wdy[1], x1, wdy[2] * x2));          \
    const v2 wsy = vfma(wsh[0], x0, vfma(wsh[1], x1, wsh[2] * x2));          \
    const v2 exd = ex0 - P0;                                                 \
    const v2 eyd = ey0 - P1;                                                 \
    const v2 exy = wsy - PS;                                                 \
    const v2 szd = exd + eyd;           /* = -ezd, exact */                  \
    const v2 ua = vfma(eyd, eyd, exd * exd);                                 \
    const v2 ub = vfma(exy, exy, szd * szd);                                 \
    v2 u = ua + ub;                                                          \
    u = vmax(u, (v2){1e-30f, 1e-30f});                                       \
    v2 rq;                                                                   \
    rq.x = __builtin_amdgcn_rsqf(u.x);                                       \
    rq.y = __builtin_amdgcn_rsqf(u.y);                                       \
    const v2 gm = vmax(vfma(-YY, rq, (v2){1.0f, 1.0f}), (v2){0.0f, 0.0f});   \
    const v2 su = u * rq;               /* sqrt(u), Y side-chain only */     \
    const v2 k  = K3P * gm;                                                  \
    YY = vfma((v2){HP, HP}, gm * su, YY); /* fY = gm*su = max(su-Y,0) */     \
    const v2 kdx = k * exd;                                                  \
    const v2 kdy = k * eyd;                                                  \
    const v2 kdp = k * exy;                                                  \
    P0 += kdx;                                                               \
    P1 += kdy;                                                               \
    PS += kdp;                                                               \
    Z0 = vfma(w2p[0][0], kdx, vfma(w2p[0][1], kdy, vfma(w2p[0][2], kdp, Z0)));\
    Z1 = vfma(w2p[1][0], kdx, vfma(w2p[1][1], kdy, vfma(w2p[1][2], kdp, Z1)));\
    Z2 = vfma(w2p[2][0], kdx, vfma(w2p[2][1], kdy, vfma(w2p[2][2], kdp, Z2)));\
    (rr)[0] = Z0.x + Z0.y;                                                   \
    (rr)[1] = Z1.x + Z1.y;                                                   \
    (rr)[2] = Z2.x + Z2.y;                                                   \
    (mxv) = fmaf(Mrow[0], x0s, fmaf(Mrow[1], x1s, Mrow[2] * x2s));           \
  }

#define STEP_A(X0, X1, X2, s) \
    J2_PHYS(pA0, pA1, pAs, YA, zA0, zA1, zA2, X0, X1, X2, rA + 3*(s), mxA[s])
#define STEP_B(X0, X1, X2, s) \
    J2_PHYS(pB0, pB1, pBs, YB, zB0, zB1, zB2, X0, X1, X2, rB + 3*(s), mxB[s])

    float4 A0 = xvA[0], A1 = xvA[1], A2 = xvA[2];
    float4 A3 = xvA[3], A4 = xvA[4], A5 = xvA[5];
    float4 B0 = xvB[0], B1 = xvB[1], B2 = xvB[2];
    float4 B3 = xvB[3], B4 = xvB[4], B5 = xvB[5];

    for (int tb = 0; tb < TSTEPS / 8; ++tb) {
        // distance-1 prefetch; last iteration re-loads the same block (no OOB)
        const int nb = (tb < TSTEPS / 8 - 1) ? (6 * tb + 6) : (6 * tb);
        float4 An0 = xvA[nb + 0], An1 = xvA[nb + 1], An2 = xvA[nb + 2];
        float4 An3 = xvA[nb + 3], An4 = xvA[nb + 4], An5 = xvA[nb + 5];
        float4 Bn0 = xvB[nb + 0], Bn1 = xvB[nb + 1], Bn2 = xvB[nb + 2];
        float4 Bn3 = xvB[nb + 3], Bn4 = xvB[nb + 4], Bn5 = xvB[nb + 5];

        float rA[24], mxA[8], rB[24], mxB[8];
        // textually interleaved A/B steps: two independent chains in-window
        STEP_A(A0.x, A0.y, A0.z, 0);  STEP_B(B0.x, B0.y, B0.z, 0);
        STEP_A(A0.w, A1.x, A1.y, 1);  STEP_B(B0.w, B1.x, B1.y, 1);
        STEP_A(A1.z, A1.w, A2.x, 2);  STEP_B(B1.z, B1.w, B2.x, 2);
        STEP_A(A2.y, A2.z, A2.w, 3);  STEP_B(B2.y, B2.z, B2.w, 3);
        STEP_A(A3.x, A3.y, A3.z, 4);  STEP_B(B3.x, B3.y, B3.z, 4);
        STEP_A(A3.w, A4.x, A4.y, 5);  STEP_B(B3.w, B4.x, B4.y, 5);
        STEP_A(A4.z, A4.w, A5.x, 6);  STEP_B(B4.z, B4.w, B5.x, 6);
        STEP_A(A5.y, A5.z, A5.w, 7);  STEP_B(B5.y, B5.z, B5.w, 7);

        DPP_BFLY24(rA[0],  rA[1],  rA[2],  rA[3],  rA[4],  rA[5],
                   rA[6],  rA[7],  rA[8],  rA[9],  rA[10], rA[11],
                   rA[12], rA[13], rA[14], rA[15], rA[16], rA[17],
                   rA[18], rA[19], rA[20], rA[21], rA[22], rA[23]);
        DPP_BFLY24(rB[0],  rB[1],  rB[2],  rB[3],  rB[4],  rB[5],
                   rB[6],  rB[7],  rB[8],  rB[9],  rB[10], rB[11],
                   rB[12], rB[13], rB[14], rB[15], rB[16], rB[17],
                   rB[18], rB[19], rB[20], rB[21], rB[22], rB[23]);

        if (wact) {
            // lane l writes component l: out = M.x - 2MU * Z
            #pragma unroll
            for (int s = 0; s < 8; ++s) {
                float za = (l == 0) ? rA[3*s] : ((l == 1) ? rA[3*s+1] : rA[3*s+2]);
                float zb = (l == 0) ? rB[3*s] : ((l == 1) ? rB[3*s+1] : rB[3*s+2]);
                oblA[24 * tb + 3 * s] = fmaf(-TWO_MU, za, mxA[s]);
                oblB[24 * tb + 3 * s] = fmaf(-TWO_MU, zb, mxB[s]);
            }
        }

        A0 = An0; A1 = An1; A2 = An2; A3 = An3; A4 = An4; A5 = An5;
        B0 = Bn0; B1 = Bn1; B2 = Bn2; B3 = Bn3; B4 = Bn4; B5 = Bn5;
    }
#undef STEP_A
#undef STEP_B
#undef J2_PHYS
}

extern "C" void kernel_launch(void* const* d_in, const int* in_sizes, int n_in,
                              void* d_out, int out_size, void* d_ws, size_t ws_size,
                              hipStream_t stream) {
    const float* x  = (const float*)d_in[0];
    const float* W1 = (const float*)d_in[1];
    const float* W2 = (const float*)d_in[2];
    float* out = (float*)d_out;

    const int B = 16384;
    dim3 grid(B / BPB);   // 256 blocks -> 1 block/CU, 1 wave/SIMD, 2 chains/thread
    dim3 block(BLOCK);
    prnn_j2_kernel<<<grid, block, 0, stream>>>(x, W1, W2, out);
}